// Round 5
// baseline (4226.190 us; speedup 1.0000x reference)
//
#include <hip/hip_runtime.h>
#include <hip/hip_bf16.h>

// R5: chunked-parallel Kalman filter, R4's literal step math (proven bounded
// over 20000 steps), f32 output (harness reads d_out per reference dtype =
// float32; R2/R3's "e32" absmax decoded as bf16-half-pairs read as f32).

#define T_STEPS 20000
#define NOBS 16
#define NST 32
#define CHUNKS 500
#define CHUNK_LEN 40
#define WARMUP 256
#define MEANS_SZ (T_STEPS * NST)

static_assert(CHUNKS * CHUNK_LEN == T_STEPS, "chunk coverage");

#define ENC_F32 0
#define ENC_BF16 1
#define MENC_I32 0
#define MENC_U8 1
#define MENC_BF16 2
#define MENC_F32 3
#define MENC_I64 4

__device__ __forceinline__ float load_f(const void* p, int idx, int enc) {
    if (enc == ENC_F32) return ((const float*)p)[idx];
    unsigned int u = ((const unsigned short*)p)[idx];
    u <<= 16;
    float f;
    __builtin_memcpy(&f, &u, 4);
    return f;
}

// Output dtype = reference output dtype = float32.
__device__ __forceinline__ void store_out(void* p, int idx, float v) {
    if (!__builtin_isfinite(v)) v = 0.0f;  // keep failure signatures finite/localizable
    ((float*)p)[idx] = v;
}

__device__ __forceinline__ float load_mask(const void* p, int idx, int menc) {
    switch (menc) {
        case MENC_I32:  return ((const int*)p)[idx] != 0 ? 1.0f : 0.0f;
        case MENC_U8:   return ((const unsigned char*)p)[idx] != 0 ? 1.0f : 0.0f;
        case MENC_BF16: { unsigned short h = ((const unsigned short*)p)[idx];
                          return (h & 0x7FFF) != 0 ? 1.0f : 0.0f; }
        case MENC_F32:  return ((const float*)p)[idx] != 0.0f ? 1.0f : 0.0f;
        default:        return ((const long long*)p)[idx] != 0 ? 1.0f : 0.0f;
    }
}

// packed-bf16 vs f32 storage: even ushort halves nonzero+plausible only for packed bf16.
__device__ int detect_float_enc(const void* obsp) {
    const unsigned short* ph = (const unsigned short*)obsp;
    int plaus_nz = 0;
    for (int e = 0; e < 64; e += 2) {
        unsigned short h = ph[e];
        int ex = (h >> 7) & 0xFF;
        if (h != 0 && ex >= 100 && ex <= 140) plaus_nz++;
    }
    return (plaus_nz >= 24) ? ENC_BF16 : ENC_F32;
}

__device__ int detect_mask_enc(const void* maskp) {
    const unsigned char* pb = (const unsigned char*)maskp;
    bool only01 = true;
    bool nz_mod4_1 = false, nz_mod4_not0 = false, nz_mod8_4 = false;
    for (int j = 0; j < 128; j++) {
        unsigned char b = pb[j];
        if (b > 1) only01 = false;
        if (b) {
            if ((j & 3) == 1) nz_mod4_1 = true;
            if ((j & 3) != 0) nz_mod4_not0 = true;
            if ((j & 7) == 4) nz_mod8_4 = true;
        }
    }
    if (only01) {
        if (nz_mod4_not0) return MENC_U8;
        if (nz_mod8_4)    return MENC_I32;
        return MENC_I64;
    }
    return nz_mod4_1 ? MENC_BF16 : MENC_F32;
}

__launch_bounds__(256)
__global__ void kalman_chunks(const void* __restrict__ obs, const void* __restrict__ mask,
                              const void* __restrict__ Fv, const void* __restrict__ bv,
                              const void* __restrict__ Hv, const void* __restrict__ dv,
                              const void* __restrict__ Qraw, const void* __restrict__ Rraw,
                              const void* __restrict__ m0v, const void* __restrict__ P0raw,
                              void* __restrict__ out) {
    __shared__ float sF[NST][NST + 1];
    __shared__ float sH[NOBS][NST + 1];
    __shared__ float sQ[NST][NST + 1];
    __shared__ float sR[NOBS][NOBS + 1];
    __shared__ float sP[NST][NST + 1];
    __shared__ float sPf[NST][NST + 1];
    __shared__ float sT[NST][NST + 1];
    __shared__ float sHmP[NOBS][NST + 1];   // Hm @ P (literal)
    __shared__ float sPHt[NST][NOBS + 1];   // P @ Hm^T (literal)
    __shared__ float sK[NST][NOBS + 1];
    __shared__ float sA[NOBS][2 * NOBS + 1];
    __shared__ float sB[NOBS][2 * NOBS + 1];
    __shared__ float sb[NST], sd[NOBS], sm[NST], smf[NST], smnew[NST];
    __shared__ float yv[NOBS], mfv[NOBS], vv[NOBS];
    __shared__ int sEnc[2];

    const int tid = threadIdx.x;
    const int c = blockIdx.x;

    if (tid == 0) {
        sEnc[0] = detect_float_enc(obs);
        sEnc[1] = detect_mask_enc(mask);
    }
    __syncthreads();
    const int fe = sEnc[0];
    const int me = sEnc[1];

    // ---- static loads (sT, sA, sPf as temporaries for raw Chol factors) ----
    for (int idx = tid; idx < NST * NST; idx += 256) {
        int i = idx >> 5, j = idx & 31;
        sF[i][j] = load_f(Fv, idx, fe);
        sT[i][j] = load_f(Qraw, idx, fe);
        sPf[i][j] = load_f(P0raw, idx, fe);
    }
    for (int idx = tid; idx < NOBS * NST; idx += 256) {
        int i = idx >> 5, j = idx & 31;
        sH[i][j] = load_f(Hv, idx, fe);
    }
    for (int idx = tid; idx < NOBS * NOBS; idx += 256) {
        int i = idx >> 4, j = idx & 15;
        sA[i][j] = load_f(Rraw, idx, fe);
    }
    if (tid < NST) sb[tid] = load_f(bv, tid, fe);
    if (tid < NOBS) sd[tid] = load_f(dv, tid, fe);
    __syncthreads();

    const int s_c = c * CHUNK_LEN;
    const int t_end = s_c + CHUNK_LEN;
    int t_begin = s_c - WARMUP;
    bool exact = false;
    if (t_begin <= 0) { t_begin = 0; exact = true; }

    // ---- posdef init: Q, R; P = P0 (exact) or I (warm); m = m0 or 0 ----
    for (int idx = tid; idx < NST * NST; idx += 256) {
        int i = idx >> 5, j = idx & 31;
        int kmax = min(i, j);
        float acc = 0.0f;
        for (int k = 0; k <= kmax; k++) acc += sT[i][k] * sT[j][k];
        sQ[i][j] = acc;
        float pv;
        if (exact) {
            float a2 = 0.0f;
            for (int k = 0; k <= kmax; k++) a2 += sPf[i][k] * sPf[j][k];
            pv = a2;
        } else {
            pv = (i == j) ? 1.0f : 0.0f;
        }
        sP[i][j] = pv;
    }
    for (int idx = tid; idx < NOBS * NOBS; idx += 256) {
        int i = idx >> 4, j = idx & 15;
        int kmax = min(i, j);
        float acc = 0.0f;
        for (int k = 0; k <= kmax; k++) acc += sA[i][k] * sA[j][k];
        sR[i][j] = acc;
    }
    if (tid < NST) sm[tid] = exact ? load_f(m0v, tid, fe) : 0.0f;
    __syncthreads();

    for (int t = t_begin; t < t_end; t++) {
        // L0: decode obs + mask
        if (tid < NOBS) {
            mfv[tid] = load_mask(mask, t * NOBS + tid, me);
            yv[tid] = load_f(obs, t * NOBS + tid, fe);
        }
        __syncthreads();

        // L1: HmP = Hm@P ; PHt = P@Hm^T ; innovation v
        {
            int idx = tid;
            for (int r = 0; r < 4; r++, idx += 256) {
                if (idx < 512) {
                    int j = idx >> 5, l = idx & 31;
                    float acc = 0.0f;
#pragma unroll
                    for (int k = 0; k < NST; k++) acc += sH[j][k] * sP[k][l];
                    sHmP[j][l] = acc * mfv[j];
                } else {
                    int e = idx - 512;
                    int a = e >> 4, j = e & 15;
                    float acc = 0.0f;
#pragma unroll
                    for (int k = 0; k < NST; k++) acc += sP[a][k] * sH[j][k];
                    sPHt[a][j] = acc * mfv[j];
                }
            }
            if (tid < NOBS) {
                float acc = yv[tid] - sd[tid];
#pragma unroll
                for (int k = 0; k < NST; k++) acc -= sH[tid][k] * sm[k];
                vv[tid] = acc * mfv[tid];
            }
        }
        __syncthreads();

        // L2: S = Hm@PHt + Rm into augmented [S | I]
        {
            int idx = tid;
            for (int r = 0; r < 2; r++, idx += 256) {
                int i = idx >> 5, j = idx & 31;
                float val;
                if (j < NOBS) {
                    float acc = 0.0f;
#pragma unroll
                    for (int k = 0; k < NST; k++) acc += sH[i][k] * sPHt[k][j];
                    acc *= mfv[i];
                    float rm = sR[i][j] * mfv[i] * mfv[j];
                    if (i == j) rm += 1.0f - mfv[i];
                    val = acc + rm;
                } else {
                    val = ((j - NOBS) == i) ? 1.0f : 0.0f;
                }
                sA[i][j] = val;
            }
        }
        __syncthreads();

        // L3: Gauss-Jordan (16 pivots, parity-unrolled double buffer)
        for (int k = 0; k < NOBS; k += 2) {
            {
                float p = sA[k][k];
                float rp = (__builtin_fabsf(p) > 1e-30f) ? (1.0f / p) : 0.0f;
                int idx = tid;
                for (int r = 0; r < 2; r++, idx += 256) {
                    int i = idx >> 5, j = idx & 31;
                    float skj = sA[k][j];
                    sB[i][j] = (i == k) ? (skj * rp)
                                        : (sA[i][j] - sA[i][k] * rp * skj);
                }
                __syncthreads();
            }
            {
                int k1 = k + 1;
                float p = sB[k1][k1];
                float rp = (__builtin_fabsf(p) > 1e-30f) ? (1.0f / p) : 0.0f;
                int idx = tid;
                for (int r = 0; r < 2; r++, idx += 256) {
                    int i = idx >> 5, j = idx & 31;
                    float skj = sB[k1][j];
                    sA[i][j] = (i == k1) ? (skj * rp)
                                         : (sB[i][j] - sB[i][k1] * rp * skj);
                }
                __syncthreads();
            }
        }

        // L4: K = PHt @ Sinv
        {
            int idx = tid;
            for (int r = 0; r < 2; r++, idx += 256) {
                int a = idx >> 4, j = idx & 15;
                float acc = 0.0f;
#pragma unroll
                for (int k = 0; k < NOBS; k++) acc += sPHt[a][k] * sA[k][NOBS + j];
                sK[a][j] = acc;
            }
        }
        __syncthreads();

        // L5: m_f = m + K v ; P_f = P - K @ HmP (literal) ; emit
        {
            const bool emit = (t >= s_c);
            if (tid < NST) {
                float acc = sm[tid];
#pragma unroll
                for (int k = 0; k < NOBS; k++) acc += sK[tid][k] * vv[k];
                smf[tid] = acc;
                if (emit) store_out(out, t * NST + tid, acc);
            }
            int idx = tid;
            for (int r = 0; r < 4; r++, idx += 256) {
                int i = idx >> 5, j = idx & 31;
                float acc = sP[i][j];
#pragma unroll
                for (int k = 0; k < NOBS; k++) acc -= sK[i][k] * sHmP[k][j];
                sPf[i][j] = acc;
                if (emit) store_out(out, MEANS_SZ + t * NST * NST + idx, acc);
            }
        }
        __syncthreads();

        // L6: T = F @ P_f ; m_next = F m_f + b
        {
            int idx = tid;
            for (int r = 0; r < 4; r++, idx += 256) {
                int i = idx >> 5, j = idx & 31;
                float acc = 0.0f;
#pragma unroll
                for (int k = 0; k < NST; k++) acc += sF[i][k] * sPf[k][j];
                sT[i][j] = acc;
            }
            if (tid < NST) {
                float acc = sb[tid];
#pragma unroll
                for (int k = 0; k < NST; k++) acc += sF[tid][k] * smf[k];
                smnew[tid] = acc;
            }
        }
        __syncthreads();

        // L7: P_next = T @ F^T + Q ; commit m
        {
            int idx = tid;
            for (int r = 0; r < 4; r++, idx += 256) {
                int i = idx >> 5, j = idx & 31;
                float acc = sQ[i][j];
#pragma unroll
                for (int k = 0; k < NST; k++) acc += sT[i][k] * sF[j][k];
                sP[i][j] = acc;
            }
            if (tid < NST) sm[tid] = smnew[tid];
        }
        __syncthreads();
    }
}

extern "C" void kernel_launch(void* const* d_in, const int* in_sizes, int n_in,
                              void* d_out, int out_size, void* d_ws, size_t ws_size,
                              hipStream_t stream) {
    (void)in_sizes; (void)n_in; (void)d_ws; (void)ws_size; (void)out_size;
    kalman_chunks<<<CHUNKS, 256, 0, stream>>>(
        d_in[0], d_in[1], d_in[2], d_in[3], d_in[4],
        d_in[5], d_in[6], d_in[7], d_in[8], d_in[9], d_out);
}

// Round 6
// 2581.152 us; speedup vs baseline: 1.6373x; 1.6373x over previous
//
#include <hip/hip_runtime.h>
#include <hip/hip_bf16.h>

// R6: 7-barrier step (was ~25). Single-wave shuffle-register Gauss-Jordan
// (no LDS, no barriers). All dot operands row-major via transposed LDS
// copies -> float4 ds_read_b128. obs/mask prefetched in P7. Grid 500x40
// unchanged (latency-bound: blocks hide each other; longer chunks = more wall).

#define T_STEPS 20000
#define NOBS 16
#define NST 32
#define CHUNKS 500
#define CHUNK_LEN 40
#define WARMUP 256
#define MEANS_SZ (T_STEPS * NST)

static_assert(CHUNKS * CHUNK_LEN == T_STEPS, "chunk coverage");

#define ENC_F32 0
#define ENC_BF16 1
#define MENC_I32 0
#define MENC_U8 1
#define MENC_BF16 2
#define MENC_F32 3
#define MENC_I64 4

__device__ __forceinline__ float load_f(const void* p, int idx, int enc) {
    if (enc == ENC_F32) return ((const float*)p)[idx];
    unsigned int u = ((const unsigned short*)p)[idx];
    u <<= 16;
    float f;
    __builtin_memcpy(&f, &u, 4);
    return f;
}

__device__ __forceinline__ void store_out(void* p, int idx, float v) {
    if (!__builtin_isfinite(v)) v = 0.0f;
    ((float*)p)[idx] = v;
}

__device__ __forceinline__ float load_mask(const void* p, int idx, int menc) {
    switch (menc) {
        case MENC_I32:  return ((const int*)p)[idx] != 0 ? 1.0f : 0.0f;
        case MENC_U8:   return ((const unsigned char*)p)[idx] != 0 ? 1.0f : 0.0f;
        case MENC_BF16: { unsigned short h = ((const unsigned short*)p)[idx];
                          return (h & 0x7FFF) != 0 ? 1.0f : 0.0f; }
        case MENC_F32:  return ((const float*)p)[idx] != 0.0f ? 1.0f : 0.0f;
        default:        return ((const long long*)p)[idx] != 0 ? 1.0f : 0.0f;
    }
}

__device__ int detect_float_enc(const void* obsp) {
    const unsigned short* ph = (const unsigned short*)obsp;
    int plaus_nz = 0;
    for (int e = 0; e < 64; e += 2) {
        unsigned short h = ph[e];
        int ex = (h >> 7) & 0xFF;
        if (h != 0 && ex >= 100 && ex <= 140) plaus_nz++;
    }
    return (plaus_nz >= 24) ? ENC_BF16 : ENC_F32;
}

__device__ int detect_mask_enc(const void* maskp) {
    const unsigned char* pb = (const unsigned char*)maskp;
    bool only01 = true;
    bool nz_mod4_1 = false, nz_mod4_not0 = false, nz_mod8_4 = false;
    for (int j = 0; j < 128; j++) {
        unsigned char b = pb[j];
        if (b > 1) only01 = false;
        if (b) {
            if ((j & 3) == 1) nz_mod4_1 = true;
            if ((j & 3) != 0) nz_mod4_not0 = true;
            if ((j & 7) == 4) nz_mod8_4 = true;
        }
    }
    if (only01) {
        if (nz_mod4_not0) return MENC_U8;
        if (nz_mod8_4)    return MENC_I32;
        return MENC_I64;
    }
    return nz_mod4_1 ? MENC_BF16 : MENC_F32;
}

__device__ __forceinline__ float dot32_f4(const float* __restrict__ a,
                                          const float* __restrict__ b) {
    float acc = 0.0f;
#pragma unroll
    for (int q = 0; q < 8; q++) {
        float4 x = *(const float4*)(a + 4 * q);
        float4 y = *(const float4*)(b + 4 * q);
        acc += x.x * y.x + x.y * y.y + x.z * y.z + x.w * y.w;
    }
    return acc;
}

__device__ __forceinline__ float dot16_f4(const float* __restrict__ a,
                                          const float* __restrict__ b) {
    float acc = 0.0f;
#pragma unroll
    for (int q = 0; q < 4; q++) {
        float4 x = *(const float4*)(a + 4 * q);
        float4 y = *(const float4*)(b + 4 * q);
        acc += x.x * y.x + x.y * y.y + x.z * y.z + x.w * y.w;
    }
    return acc;
}

__launch_bounds__(256)
__global__ void kalman_chunks(const void* __restrict__ obs, const void* __restrict__ mask,
                              const void* __restrict__ Fv, const void* __restrict__ bv,
                              const void* __restrict__ Hv, const void* __restrict__ dv,
                              const void* __restrict__ Qraw, const void* __restrict__ Rraw,
                              const void* __restrict__ m0v, const void* __restrict__ P0raw,
                              void* __restrict__ out) {
    // stride 36 (mult of 4 floats -> 16B-aligned rows; 36%32=4 keeps row-start
    // banks spread). stride 20 for 16-wide rows (80B, 16B-aligned).
    __shared__ __align__(16) float sF[NST][36];
    __shared__ __align__(16) float sH[NOBS][36];
    __shared__ __align__(16) float sQ[NST][36];
    __shared__ __align__(16) float sP[NST][36];
    __shared__ __align__(16) float sPT[NST][36];   // P^T
    __shared__ __align__(16) float sPfT[NST][36];  // Pf^T
    __shared__ __align__(16) float sT[NST][36];
    __shared__ __align__(16) float sHmP[NOBS][36];
    __shared__ __align__(16) float sPHt[NST][20];
    __shared__ __align__(16) float sHmPT[NST][20]; // (HmP)^T
    __shared__ __align__(16) float sK[NST][20];
    __shared__ __align__(16) float sSinvT[NOBS][20];
    __shared__ float sR[NOBS][17];
    __shared__ float sS[NOBS][18];
    __shared__ __align__(16) float sb[NST], sd[NOBS], sm[NST], smf[NST], smnew[NST];
    __shared__ float yv[NOBS], mfv[NOBS], vv[NOBS];
    __shared__ int sEnc[2];

    const int tid = threadIdx.x;
    const int c = blockIdx.x;

    if (tid == 0) {
        sEnc[0] = detect_float_enc(obs);
        sEnc[1] = detect_mask_enc(mask);
    }
    __syncthreads();
    const int fe = sEnc[0];
    const int me = sEnc[1];

    // ---- static loads (sT, sPfT, sS as temporaries for raw Chol factors) ----
    for (int idx = tid; idx < NST * NST; idx += 256) {
        int i = idx >> 5, j = idx & 31;
        sF[i][j] = load_f(Fv, idx, fe);
        sT[i][j] = load_f(Qraw, idx, fe);
        sPfT[i][j] = load_f(P0raw, idx, fe);
    }
    for (int idx = tid; idx < NOBS * NST; idx += 256) {
        int i = idx >> 5, j = idx & 31;
        sH[i][j] = load_f(Hv, idx, fe);
    }
    for (int idx = tid; idx < NOBS * NOBS; idx += 256) {
        int i = idx >> 4, j = idx & 15;
        sS[i][j] = load_f(Rraw, idx, fe);
    }
    if (tid < NST) sb[tid] = load_f(bv, tid, fe);
    if (tid < NOBS) sd[tid] = load_f(dv, tid, fe);
    __syncthreads();

    const int s_c = c * CHUNK_LEN;
    const int t_end = s_c + CHUNK_LEN;
    int t_begin = s_c - WARMUP;
    bool exact = false;
    if (t_begin <= 0) { t_begin = 0; exact = true; }

    // ---- posdef init: Q, R; P (+P^T) = P0 or I; m = m0 or 0; prefetch t_begin ----
    for (int idx = tid; idx < NST * NST; idx += 256) {
        int i = idx >> 5, j = idx & 31;
        int kmax = min(i, j);
        float acc = 0.0f;
        for (int k = 0; k <= kmax; k++) acc += sT[i][k] * sT[j][k];
        sQ[i][j] = acc;
        float pv;
        if (exact) {
            float a2 = 0.0f;
            for (int k = 0; k <= kmax; k++) a2 += sPfT[i][k] * sPfT[j][k];
            pv = a2;
        } else {
            pv = (i == j) ? 1.0f : 0.0f;
        }
        sP[i][j] = pv;
        sPT[j][i] = pv;
    }
    for (int idx = tid; idx < NOBS * NOBS; idx += 256) {
        int i = idx >> 4, j = idx & 15;
        int kmax = min(i, j);
        float acc = 0.0f;
        for (int k = 0; k <= kmax; k++) acc += sS[i][k] * sS[j][k];
        sR[i][j] = acc;
    }
    if (tid < NST) sm[tid] = exact ? load_f(m0v, tid, fe) : 0.0f;
    if (tid >= 64 && tid < 64 + NOBS) mfv[tid - 64] = load_mask(mask, t_begin * NOBS + (tid - 64), me);
    if (tid >= 96 && tid < 96 + NOBS) yv[tid - 96] = load_f(obs, t_begin * NOBS + (tid - 96), fe);
    __syncthreads();

    for (int t = t_begin; t < t_end; t++) {
        // B1: HmP = Hm@P (via P^T, both rows) ; PHt = P@Hm^T ; innovation v
        {
#pragma unroll
            for (int r = 0; r < 4; r++) {
                int idx = tid + (r << 8);
                if (idx < 512) {
                    int j = idx >> 5, l = idx & 31;
                    float acc = dot32_f4(&sH[j][0], &sPT[l][0]) * mfv[j];
                    sHmP[j][l] = acc;
                    sHmPT[l][j] = acc;
                } else {
                    int e = idx - 512;
                    int a = e >> 4, j = e & 15;
                    sPHt[a][j] = dot32_f4(&sP[a][0], &sH[j][0]) * mfv[j];
                }
            }
            if (tid < NOBS)
                vv[tid] = mfv[tid] * (yv[tid] - sd[tid] - dot32_f4(&sH[tid][0], sm));
        }
        __syncthreads();

        // B2: S = (HmP)@Hm^T + Rm   (exact algebra, no symmetry assumption)
        {
            int i = tid >> 4, j = tid & 15;
            float acc = dot32_f4(&sHmP[i][0], &sH[j][0]) * mfv[j];
            float rm = sR[i][j] * mfv[i] * mfv[j];
            if (i == j) rm += 1.0f - mfv[i];
            sS[i][j] = acc + rm;
        }
        __syncthreads();

        // B3: single-wave register Gauss-Jordan on [S | I], shuffles only.
        // lane: row r = lane>>2, col-group cg = lane&3 (cols cg*8..+8 of 32).
        if (tid < 64) {
            const int r = tid >> 2, cg = tid & 3;
            float a[8];
#pragma unroll
            for (int j = 0; j < 8; j++) {
                int col = cg * 8 + j;
                a[j] = (col < NOBS) ? sS[r][col] : ((col - NOBS == r) ? 1.0f : 0.0f);
            }
#pragma unroll
            for (int k = 0; k < NOBS; k++) {
                float pivot = __shfl(a[k & 7], (k << 2) | (k >> 3), 64);
                float rp = (__builtin_fabsf(pivot) > 1e-30f) ? (1.0f / pivot) : 0.0f;
                float colk = __shfl(a[k & 7], (r << 2) | (k >> 3), 64);
                float rowk[8];
#pragma unroll
                for (int j = 0; j < 8; j++) rowk[j] = __shfl(a[j], (k << 2) | cg, 64);
                float f = colk * rp;
                bool isk = (r == k);
#pragma unroll
                for (int j = 0; j < 8; j++)
                    a[j] = isk ? (rowk[j] * rp) : (a[j] - f * rowk[j]);
            }
            if (cg >= 2) {   // cols 16..31 hold Sinv; store transposed
#pragma unroll
                for (int j = 0; j < 8; j++) sSinvT[cg * 8 + j - 16][r] = a[j];
            }
        }
        __syncthreads();

        // B4: K = PHt @ Sinv  (via Sinv^T, rows)
        {
#pragma unroll
            for (int r = 0; r < 2; r++) {
                int idx = tid + (r << 8);
                int a = idx >> 4, j = idx & 15;
                sK[a][j] = dot16_f4(&sPHt[a][0], &sSinvT[j][0]);
            }
        }
        __syncthreads();

        // B5: m_f = m + K v ; Pf = P - K@HmP (via HmP^T) ; emit
        {
            const bool emit = (t >= s_c);
            if (tid < NST) {
                float acc = sm[tid] + dot16_f4(&sK[tid][0], vv);
                smf[tid] = acc;
                if (emit) store_out(out, t * NST + tid, acc);
            }
#pragma unroll
            for (int r = 0; r < 4; r++) {
                int idx = tid + (r << 8);
                int i = idx >> 5, j = idx & 31;
                float acc = sP[i][j] - dot16_f4(&sK[i][0], &sHmPT[j][0]);
                sPfT[j][i] = acc;
                if (emit) store_out(out, MEANS_SZ + t * (NST * NST) + idx, acc);
            }
        }
        __syncthreads();

        // B6: T = F @ Pf (via Pf^T) ; m' = F m_f + b
        {
#pragma unroll
            for (int r = 0; r < 4; r++) {
                int idx = tid + (r << 8);
                int i = idx >> 5, j = idx & 31;
                sT[i][j] = dot32_f4(&sF[i][0], &sPfT[j][0]);
            }
            if (tid < NST) smnew[tid] = sb[tid] + dot32_f4(&sF[tid][0], smf);
        }
        __syncthreads();

        // B7: P' = T@F^T + Q (write P and P^T) ; commit m ; prefetch t+1
        {
#pragma unroll
            for (int r = 0; r < 4; r++) {
                int idx = tid + (r << 8);
                int i = idx >> 5, j = idx & 31;
                float acc = sQ[i][j] + dot32_f4(&sT[i][0], &sF[j][0]);
                sP[i][j] = acc;
                sPT[j][i] = acc;
            }
            if (tid < NST) sm[tid] = smnew[tid];
            int tn = t + 1;
            if (tn < t_end) {
                if (tid >= 64 && tid < 64 + NOBS)
                    mfv[tid - 64] = load_mask(mask, tn * NOBS + (tid - 64), me);
                if (tid >= 96 && tid < 96 + NOBS)
                    yv[tid - 96] = load_f(obs, tn * NOBS + (tid - 96), fe);
            }
        }
        __syncthreads();
    }
}

extern "C" void kernel_launch(void* const* d_in, const int* in_sizes, int n_in,
                              void* d_out, int out_size, void* d_ws, size_t ws_size,
                              hipStream_t stream) {
    (void)in_sizes; (void)n_in; (void)d_ws; (void)ws_size; (void)out_size;
    kalman_chunks<<<CHUNKS, 256, 0, stream>>>(
        d_in[0], d_in[1], d_in[2], d_in[3], d_in[4],
        d_in[5], d_in[6], d_in[7], d_in[8], d_in[9], d_out);
}